// Round 4
// baseline (1171.307 us; speedup 1.0000x reference)
//
#include <hip/hip_runtime.h>
#include <hip/hip_bf16.h>
#include <stdint.h>

// ---------------- problem constants ----------------
#define BATCH 2
#define SEQ   2048
#define DM    1024
#define DS    16
#define PROJ  34816          // 2*DM + 2*DM*DS
#define MTOK  4096           // BATCH*SEQ
#define KDIM  1024
#define NCHUNK 16
#define CHUNK  128           // SEQ / NCHUNK
#define NCH    32768         // BATCH*DM*DS scan channels

typedef unsigned short u16;
typedef unsigned int   u32;
typedef __attribute__((ext_vector_type(8))) __bf16 bf16x8;
typedef __attribute__((ext_vector_type(4))) float  f32x4;

// xp element load/store, overloaded on storage type (f32 primary, bf16 fallback)
__device__ __forceinline__ float ldf(const float* p) { return *p; }
__device__ __forceinline__ float ldf(const __hip_bfloat16* p) { return __bfloat162float(*p); }
__device__ __forceinline__ void stf(float* p, float v) { *p = v; }
__device__ __forceinline__ void stf(__hip_bfloat16* p, float v) { *p = __float2bfloat16(v); }

// async global->LDS, 16B per lane. LDS dest must be linear in lane (it is:
// per-thread lds ptr = base + tid*16B). Generic->AS(3) via uintptr truncation
// (LDS aperture: low 32 bits of generic addr = LDS byte offset).
__device__ __forceinline__ void gl16(const void* g, void* l) {
  __builtin_amdgcn_global_load_lds(
      (const __attribute__((address_space(1))) u32*)g,
      (__attribute__((address_space(3))) u32*)(u32)(uintptr_t)l,
      16, 0, 0);
}

__device__ __forceinline__ f32x4 mfma16(bf16x8 a, bf16x8 b, f32x4 c) {
  return __builtin_amdgcn_mfma_f32_16x16x32_bf16(a, b, c, 0, 0, 0);
}

// ---------------- split f32 -> bf16 hi + bf16 lo ----------------
__global__ __launch_bounds__(256)
void split_kernel(const float* __restrict__ src, u16* __restrict__ hi,
                  u16* __restrict__ lo, int n4) {
  int i = blockIdx.x * 256 + threadIdx.x;
  if (i >= n4) return;
  float4 v = reinterpret_cast<const float4*>(src)[i];
  ushort4 h, l;
  {
    __hip_bfloat16 bh, bl;
    bh = __float2bfloat16(v.x); bl = __float2bfloat16(v.x - __bfloat162float(bh));
    h.x = *(u16*)&bh; l.x = *(u16*)&bl;
    bh = __float2bfloat16(v.y); bl = __float2bfloat16(v.y - __bfloat162float(bh));
    h.y = *(u16*)&bh; l.y = *(u16*)&bl;
    bh = __float2bfloat16(v.z); bl = __float2bfloat16(v.z - __bfloat162float(bh));
    h.z = *(u16*)&bh; l.z = *(u16*)&bl;
    bh = __float2bfloat16(v.w); bl = __float2bfloat16(v.w - __bfloat162float(bh));
    h.w = *(u16*)&bh; l.w = *(u16*)&bl;
  }
  reinterpret_cast<ushort4*>(hi)[i] = h;
  reinterpret_cast<ushort4*>(lo)[i] = l;
}

// ---------------- GEMM: xp = x @ W^T + b (3-product bf16 emulation) -------
// m97 structure: 128x128 tile, BK=32, 4 waves (2x2), each wave 64x64 (4x4
// frags of 16x16x32). 3 MFMAs per frag pair: hi*hi + hi*lo + lo*hi.
// Epilogue: +bias, softplus on delta columns [DM, 2*DM).
#define BM 128
#define BN 128
#define BK 32

template <typename OutT>
__global__ __launch_bounds__(256, 2)
void gemm_kernel(const u16* __restrict__ xHi, const u16* __restrict__ xLo,
                 const u16* __restrict__ wHi, const u16* __restrict__ wLo,
                 const float* __restrict__ bias, OutT* __restrict__ xp) {
  __shared__ __align__(16) u16 sAh[BM * BK];
  __shared__ __align__(16) u16 sAl[BM * BK];
  __shared__ __align__(16) u16 sBh[BN * BK];
  __shared__ __align__(16) u16 sBl[BN * BK];

  const int tid  = threadIdx.x;
  const int lane = tid & 63;
  const int wid  = tid >> 6;
  const int wr   = wid >> 1;      // wave row (0..1)
  const int wc   = wid & 1;       // wave col (0..1)

  const int bid = blockIdx.x;
  const int mt  = bid & 31;       // m fastest: consecutive blocks share W tile window
  const int nt  = bid >> 5;
  const int m0  = mt * BM;
  const int n0  = nt * BN;

  // staging: thread covers (row = tid>>2 of 64, k-seg = (tid&3)*8)
  const int srow = tid >> 2;
  const int scol = (tid & 3) * 8;
  const u16* gAh = xHi + (size_t)(m0 + srow) * KDIM + scol;
  const u16* gAl = xLo + (size_t)(m0 + srow) * KDIM + scol;
  const u16* gBh = wHi + (size_t)(n0 + srow) * KDIM + scol;
  const u16* gBl = wLo + (size_t)(n0 + srow) * KDIM + scol;
  u16* lAh = sAh + tid * 8;   // == row*BK + colseg, linear in tid
  u16* lAl = sAl + tid * 8;
  u16* lBh = sBh + tid * 8;
  u16* lBl = sBl + tid * 8;

  f32x4 acc[4][4] = {};

  const int fr = lane & 15;
  const int kq = (lane >> 4) * 8;

  for (int kt = 0; kt < KDIM / BK; ++kt) {
    const int k0 = kt * BK;
    gl16(gAh + k0, lAh);  gl16(gAh + 64 * KDIM + k0, lAh + 64 * BK);
    gl16(gAl + k0, lAl);  gl16(gAl + 64 * KDIM + k0, lAl + 64 * BK);
    gl16(gBh + k0, lBh);  gl16(gBh + 64 * KDIM + k0, lBh + 64 * BK);
    gl16(gBl + k0, lBl);  gl16(gBl + 64 * KDIM + k0, lBl + 64 * BK);
    __syncthreads();   // compiler emits s_waitcnt vmcnt(0) before s_barrier

    bf16x8 ah[4], al[4], bh[4], bl[4];
#pragma unroll
    for (int i = 0; i < 4; ++i) {
      ah[i] = *(const bf16x8*)&sAh[(wr * 64 + i * 16 + fr) * BK + kq];
      al[i] = *(const bf16x8*)&sAl[(wr * 64 + i * 16 + fr) * BK + kq];
      bh[i] = *(const bf16x8*)&sBh[(wc * 64 + i * 16 + fr) * BK + kq];
      bl[i] = *(const bf16x8*)&sBl[(wc * 64 + i * 16 + fr) * BK + kq];
    }
#pragma unroll
    for (int mi = 0; mi < 4; ++mi)
#pragma unroll
      for (int ni = 0; ni < 4; ++ni) {
        acc[mi][ni] = mfma16(ah[mi], bh[ni], acc[mi][ni]);
        acc[mi][ni] = mfma16(ah[mi], bl[ni], acc[mi][ni]);
        acc[mi][ni] = mfma16(al[mi], bh[ni], acc[mi][ni]);
      }
    __syncthreads();
  }

  // epilogue: C/D layout col = lane&15 (n), row = (lane>>4)*4 + j (m)
  const int rq = (lane >> 4) * 4;
#pragma unroll
  for (int mi = 0; mi < 4; ++mi) {
#pragma unroll
    for (int ni = 0; ni < 4; ++ni) {
      const int col = n0 + wc * 64 + ni * 16 + fr;
      const float bv = bias[col];
      const bool isdelta = (col >= DM) && (col < 2 * DM);
      const int row = m0 + wr * 64 + mi * 16 + rq;
#pragma unroll
      for (int j = 0; j < 4; ++j) {
        float v = acc[mi][ni][j] + bv;
        if (isdelta) v = (v > 20.f) ? v : log1pf(__expf(v));
        stf(&xp[(size_t)(row + j) * PROJ + col], v);
      }
    }
  }
}

// ---------------- scan phase 1: per-chunk (prod a, local h) ----------------
// block = 256 threads = 16 d x 16 n; grid = BATCH * 64 d-tiles * NCHUNK
template <typename InT>
__global__ __launch_bounds__(256)
void scan_phase1(const InT* __restrict__ xp, const float* __restrict__ A,
                 float* __restrict__ P, float* __restrict__ Hl) {
  const int bidx = blockIdx.x;
  const int c  = bidx & 15;
  const int dt = (bidx >> 4) & 63;
  const int b  = bidx >> 10;
  const int tid = threadIdx.x;
  const int n  = tid & 15;
  const int dl = tid >> 4;
  const int d  = dt * 16 + dl;

  const float Ad = A[d * DS + n];
  const size_t row0 = ((size_t)(b * SEQ) + c * CHUNK) * PROJ;
  const InT* pu = xp + row0 + d;
  const InT* pq = xp + row0 + DM + d;              // softplus(delta), from epilogue
  const InT* pB = xp + row0 + 2 * DM + d * DS + n;

  float p = 1.f, h = 0.f;
  for (int t = 0; t < CHUNK; ++t) {
    float u  = ldf(pu);
    float dq = ldf(pq);
    float Bv = ldf(pB);
    float a  = __expf(Ad * dq);
    h = a * h + Bv * u;
    p *= a;
    pu += PROJ; pq += PROJ; pB += PROJ;
  }
  const int ch = ((b * DM + d) * DS + n);
  P[(size_t)c * NCH + ch]  = p;
  Hl[(size_t)c * NCH + ch] = h;
}

// ---------------- scan phase 2: prefix over chunks ----------------
__global__ __launch_bounds__(256)
void scan_phase2(const float* __restrict__ P, const float* __restrict__ Hl,
                 float* __restrict__ Hst) {
  const int ch = blockIdx.x * 256 + threadIdx.x;
  float h = 0.f;
  for (int c = 0; c < NCHUNK; ++c) {
    Hst[(size_t)c * NCH + ch] = h;
    h = P[(size_t)c * NCH + ch] * h + Hl[(size_t)c * NCH + ch];
  }
}

// ---------------- scan phase 3: replay with start state, emit y ------------
template <typename InT>
__global__ __launch_bounds__(256)
void scan_phase3(const InT* __restrict__ xp, const float* __restrict__ A,
                 const float* __restrict__ Dv, const float* __restrict__ Hst,
                 float* __restrict__ y) {
  const int bidx = blockIdx.x;
  const int c  = bidx & 15;
  const int dt = (bidx >> 4) & 63;
  const int b  = bidx >> 10;
  const int tid = threadIdx.x;
  const int n  = tid & 15;
  const int dl = tid >> 4;
  const int d  = dt * 16 + dl;

  const float Ad = A[d * DS + n];
  const float Dd = Dv[d];
  const int ch = ((b * DM + d) * DS + n);
  float h = Hst[(size_t)c * NCH + ch];

  const int t0 = c * CHUNK;
  const size_t row0 = ((size_t)(b * SEQ) + t0) * PROJ;
  const InT* pu = xp + row0 + d;
  const InT* pq = xp + row0 + DM + d;
  const InT* pB = xp + row0 + 2 * DM + d * DS + n;
  const InT* pC = pB + DM * DS;
  float* py = y + ((size_t)(b * SEQ) + t0) * DM + d;

  for (int t = 0; t < CHUNK; ++t) {
    float u  = ldf(pu);
    float dq = ldf(pq);
    float Bv = ldf(pB);
    float Cv = ldf(pC);
    float a  = __expf(Ad * dq);
    h = a * h + Bv * u;
    float ph = Cv * h;
    ph += __shfl_xor(ph, 1);
    ph += __shfl_xor(ph, 2);
    ph += __shfl_xor(ph, 4);
    ph += __shfl_xor(ph, 8);
    if (n == 0) *py = ph + Dd * u;
    pu += PROJ; pq += PROJ; pB += PROJ; pC += PROJ; py += DM;
  }
}

// ---------------- launch ----------------
extern "C" void kernel_launch(void* const* d_in, const int* in_sizes, int n_in,
                              void* d_out, int out_size, void* d_ws, size_t ws_size,
                              hipStream_t stream) {
  const float* x  = (const float*)d_in[0];
  const float* W  = (const float*)d_in[1];
  const float* b  = (const float*)d_in[2];
  const float* A  = (const float*)d_in[3];
  const float* Dv = (const float*)d_in[4];
  float* y = (float*)d_out;

  char* ws = (char*)d_ws;
  size_t off = 0;
  auto alloc = [&](size_t bytes) {
    void* p = ws + off;
    off += (bytes + 255) & ~(size_t)255;
    return p;
  };

  u16* xHi = (u16*)alloc((size_t)MTOK * KDIM * sizeof(u16));
  u16* xLo = (u16*)alloc((size_t)MTOK * KDIM * sizeof(u16));
  u16* wHi = (u16*)alloc((size_t)PROJ * KDIM * sizeof(u16));
  u16* wLo = (u16*)alloc((size_t)PROJ * KDIM * sizeof(u16));
  float* P   = (float*)alloc((size_t)NCHUNK * NCH * sizeof(float));
  float* Hl  = (float*)alloc((size_t)NCHUNK * NCH * sizeof(float));
  float* Hst = (float*)alloc((size_t)NCHUNK * NCH * sizeof(float));
  // xp last so its size can flex on available workspace.
  // NOTE: no unsigned subtraction — ws_size may be smaller than off.
  const size_t xp_elems = (size_t)MTOK * PROJ;
  const bool xp_f32 = ws_size >= off + xp_elems * sizeof(float);
  void* xp = alloc(xp_elems * (xp_f32 ? sizeof(float) : sizeof(__hip_bfloat16)));

  // split x and W into bf16 hi/lo
  split_kernel<<<(MTOK * KDIM / 4 + 255) / 256, 256, 0, stream>>>(x, xHi, xLo, MTOK * KDIM / 4);
  split_kernel<<<(PROJ * KDIM / 4 + 255) / 256, 256, 0, stream>>>(W, wHi, wLo, PROJ * KDIM / 4);

  const int gemm_grid = (MTOK / BM) * (PROJ / BN);
  const int scan_grid = BATCH * 64 * NCHUNK;

  if (xp_f32) {
    float* xpf = (float*)xp;
    gemm_kernel<float><<<gemm_grid, 256, 0, stream>>>(xHi, xLo, wHi, wLo, b, xpf);
    scan_phase1<float><<<scan_grid, 256, 0, stream>>>(xpf, A, P, Hl);
    scan_phase2<<<NCH / 256, 256, 0, stream>>>(P, Hl, Hst);
    scan_phase3<float><<<scan_grid, 256, 0, stream>>>(xpf, A, Dv, Hst, y);
  } else {
    __hip_bfloat16* xpb = (__hip_bfloat16*)xp;
    gemm_kernel<__hip_bfloat16><<<gemm_grid, 256, 0, stream>>>(xHi, xLo, wHi, wLo, b, xpb);
    scan_phase1<__hip_bfloat16><<<scan_grid, 256, 0, stream>>>(xpb, A, P, Hl);
    scan_phase2<<<NCH / 256, 256, 0, stream>>>(P, Hl, Hst);
    scan_phase3<__hip_bfloat16><<<scan_grid, 256, 0, stream>>>(xpb, A, Dv, Hst, y);
  }
}